// Round 1
// 1642.234 us; speedup vs baseline: 1.1960x; 1.1960x over previous
//
#include <hip/hip_runtime.h>
#include <stdint.h>

// Problem constants (fixed by reference)
#define VOC 32000
#define HD  768
#define NHD 12
#define DH  64
#define FF  3072
#define NL  6
#define BB  4
#define SS  512

typedef __bf16 bf16;
typedef __attribute__((ext_vector_type(8))) __bf16 bf16x8;
typedef __attribute__((ext_vector_type(4))) float f32x4;

// async global->LDS, 16B per lane. LDS dest must be wave-uniform base; HW adds lane*16.
__device__ __forceinline__ void ld_g2l_16(const bf16* g, bf16* lds_base) {
  __builtin_amdgcn_global_load_lds(
      (const __attribute__((address_space(1))) uint32_t*)g,
      (__attribute__((address_space(3))) uint32_t*)lds_base,
      16, 0, 0);
}

// ---------------------------------------------------------------------------
// Generic bf16 MFMA GEMM: C[M,N] = alpha * A[M,K] @ Bt[N,K]^T (+bias)(+res)(relu)
// BM=128 fixed, BN in {128,64}. 256 threads = 4 waves (2x2), 16x16x32 bf16 MFMA.
// Batched over blockIdx.z with (inner,outer) strides: z = zo*z_inner + zi.
// ---------------------------------------------------------------------------
template<int BN, bool RELU>
__global__ __launch_bounds__(256)
void gemm_kernel(const bf16* __restrict__ A, const bf16* __restrict__ B,
                 int K, int lda, int ldb, int ldc, int z_inner,
                 long long sAi, long long sAo, long long sBi, long long sBo,
                 long long sCi, long long sCo,
                 const float* __restrict__ bias, int sBias,
                 const float* __restrict__ res, float alpha,
                 float* __restrict__ outF, bf16* __restrict__ outB)
{
  constexpr int BM = 128, BK = 32;
  __shared__ bf16 As[BM * BK];
  __shared__ bf16 Bs[BN * BK];

  const int zi = blockIdx.z % z_inner;
  const int zo = blockIdx.z / z_inner;

  const bf16* Ab = A + (long long)zo * sAo + (long long)zi * sAi;
  const bf16* Bb = B + (long long)zo * sBo + (long long)zi * sBi;
  const long long coff = (long long)zo * sCo + (long long)zi * sCi;

  const int m0 = blockIdx.y * BM;
  const int n0 = blockIdx.x * BN;
  const int t = threadIdx.x;
  const int wave = t >> 6;
  const int lane = t & 63;
  const int wm = (wave >> 1) * 64;        // wave row offset in tile
  const int wn = (wave & 1) * (BN / 2);   // wave col offset in tile
  const int lr = lane & 15;               // A-row / B-col / C-col within 16
  const int ko = (lane >> 4) * 8;         // k-octet

  constexpr int NACC = BN / 32;           // 16-col tiles per wave
  f32x4 acc[4][NACC];
  const f32x4 zero4 = {0.f, 0.f, 0.f, 0.f};
#pragma unroll
  for (int i = 0; i < 4; ++i)
#pragma unroll
    for (int j = 0; j < NACC; ++j) acc[i][j] = zero4;

  constexpr int CA = (BM * BK / 8) / 256; // 16B chunks per thread (A)
  constexpr int CB = (BN * BK / 8) / 256; // (B)

  for (int k0 = 0; k0 < K; k0 += BK) {
    __syncthreads();
#pragma unroll
    for (int c = 0; c < CA; ++c) {
      int chunk = c * 256 + t;
      int r = chunk >> 2;
      int kk = (chunk & 3) << 3;
      ld_g2l_16(Ab + (long long)(m0 + r) * lda + (k0 + kk),
                &As[(c * 256 + wave * 64) * 8]);
    }
#pragma unroll
    for (int c = 0; c < CB; ++c) {
      int chunk = c * 256 + t;
      int r = chunk >> 2;
      int kk = (chunk & 3) << 3;
      ld_g2l_16(Bb + (long long)(n0 + r) * ldb + (k0 + kk),
                &Bs[(c * 256 + wave * 64) * 8]);
    }
    __syncthreads();

    bf16x8 af[4];
#pragma unroll
    for (int mi = 0; mi < 4; ++mi)
      af[mi] = *(const bf16x8*)&As[(wm + mi * 16 + lr) * BK + ko];
    bf16x8 bfr[NACC];
#pragma unroll
    for (int ni = 0; ni < NACC; ++ni)
      bfr[ni] = *(const bf16x8*)&Bs[(wn + ni * 16 + lr) * BK + ko];
#pragma unroll
    for (int mi = 0; mi < 4; ++mi)
#pragma unroll
      for (int ni = 0; ni < NACC; ++ni)
        acc[mi][ni] = __builtin_amdgcn_mfma_f32_16x16x32_bf16(
            af[mi], bfr[ni], acc[mi][ni], 0, 0, 0);
  }

  // Epilogue. C/D layout: col = lane&15, row = (lane>>4)*4 + reg  [m89/m91]
  const int r4 = (lane >> 4) * 4;
#pragma unroll
  for (int ni = 0; ni < NACC; ++ni) {
    const int col = n0 + wn + ni * 16 + lr;
    float bv = bias ? bias[(long long)zi * sBias + col] : 0.f;
#pragma unroll
    for (int mi = 0; mi < 4; ++mi) {
#pragma unroll
      for (int r = 0; r < 4; ++r) {
        const int row = m0 + wm + mi * 16 + r4 + r;
        const long long idx = coff + (long long)row * ldc + col;
        float v = acc[mi][ni][r] * alpha + bv;
        if (res) v += res[idx];
        if (RELU) v = fmaxf(v, 0.f);
        if (outF) outF[idx] = v;
        if (outB) outB[idx] = (bf16)v;
      }
    }
  }
}

// ---------------------------------------------------------------------------
// Fused attention scores + mask + softmax.
// One block = 64 q-rows for one (b,h); 4 waves, each wave owns 16 q-rows and
// the FULL 512-col S row-strip in registers (32x f32x4 acc).
// K [512][64] staged in exactly 64KB LDS with source-XOR swizzle (16B units:
// chunk c16 within a row holds global c16^(row&7)) so ds_read_b128 of
// 16 different rows at one k-slot is bank-conflict-free.
// Q fragments are read directly from global (tiny, L2-hot).
// Softmax is per-row in-wave: row r lives in the 16-lane group lane>>4,
// reduce via __shfl_xor 1/2/4/8. Writes final fp32 P (required output) and
// bf16 P for the PV GEMM. Eliminates the raw-S fp32 write+read roundtrip.
// ---------------------------------------------------------------------------
__global__ __launch_bounds__(256, 2)
void attn_fused(const bf16* __restrict__ qm, const bf16* __restrict__ km,
                const int* __restrict__ tok,
                float* __restrict__ outP, bf16* __restrict__ pb)
{
  __shared__ bf16 Ks[SS * DH];            // 64 KB
  const int z = blockIdx.y;               // b*NH + h
  const int b = z / NHD, h = z - b * NHD;
  const int q0 = blockIdx.x * 64;
  const int t = threadIdx.x;
  const int wave = t >> 6, lane = t & 63;
  const int lr = lane & 15;
  const int g = lane >> 4;
  const int ko = g * 8;

  const bf16* kb = km + (long long)b * SS * HD + h * DH;
  const bf16* qb = qm + ((long long)b * SS + q0) * HD + h * DH;

  // stage K: 512 rows x 8 16B-chunks = 4096 chunks, swizzled SOURCE address
#pragma unroll
  for (int c = 0; c < 16; ++c) {
    int chunk = c * 256 + t;
    int r = chunk >> 3;
    int sc = (chunk & 7) ^ (r & 7);
    ld_g2l_16(kb + (long long)r * HD + sc * 8, &Ks[(c * 256 + wave * 64) * 8]);
  }

  // Q fragments straight from global: row qr, k elems kk*32+ko .. +7
  const int qr = wave * 16 + lr;
  bf16x8 af[2];
#pragma unroll
  for (int kk = 0; kk < 2; ++kk)
    af[kk] = *(const bf16x8*)&qb[(long long)qr * HD + kk * 32 + ko];

  __syncthreads();

  f32x4 acc[32];
  const f32x4 zero4 = {0.f, 0.f, 0.f, 0.f};
#pragma unroll
  for (int nt = 0; nt < 32; ++nt) acc[nt] = zero4;

#pragma unroll
  for (int nt = 0; nt < 32; ++nt) {
    const int kr = nt * 16 + lr;          // K row = S column
#pragma unroll
    for (int kk = 0; kk < 2; ++kk) {
      const int e = kk * 32 + ko;         // element offset in row, 8-aligned
      bf16x8 bfr = *(const bf16x8*)&Ks[kr * DH + (((e >> 3) ^ (kr & 7)) << 3)];
      acc[nt] = __builtin_amdgcn_mfma_f32_16x16x32_bf16(af[kk], bfr, acc[nt], 0, 0, 0);
    }
  }

  // mask values per column (ref: s*scale + mask*(-10000))
  const int* tp = tok + b * SS;
  float mv[32];
#pragma unroll
  for (int nt = 0; nt < 32; ++nt)
    mv[nt] = (tp[nt * 16 + lr] == 0) ? -10000.f : 0.f;

  // scale+mask, per-row max
  float mx[4] = {-1e30f, -1e30f, -1e30f, -1e30f};
#pragma unroll
  for (int nt = 0; nt < 32; ++nt)
#pragma unroll
    for (int r = 0; r < 4; ++r) {
      float v = acc[nt][r] * 0.125f + mv[nt];
      acc[nt][r] = v;
      mx[r] = fmaxf(mx[r], v);
    }
#pragma unroll
  for (int off = 1; off < 16; off <<= 1)
#pragma unroll
    for (int r = 0; r < 4; ++r) mx[r] = fmaxf(mx[r], __shfl_xor(mx[r], off));

  float sum[4] = {0.f, 0.f, 0.f, 0.f};
#pragma unroll
  for (int nt = 0; nt < 32; ++nt)
#pragma unroll
    for (int r = 0; r < 4; ++r) {
      float p = __expf(acc[nt][r] - mx[r]);
      acc[nt][r] = p;
      sum[r] += p;
    }
#pragma unroll
  for (int off = 1; off < 16; off <<= 1)
#pragma unroll
    for (int r = 0; r < 4; ++r) sum[r] += __shfl_xor(sum[r], off);

  float inv[4];
#pragma unroll
  for (int r = 0; r < 4; ++r) inv[r] = 1.f / sum[r];

  float* orow = outP + (long long)z * SS * SS;
  bf16*  prow = pb   + (long long)z * SS * SS;
#pragma unroll
  for (int nt = 0; nt < 32; ++nt) {
    const int col = nt * 16 + lr;
#pragma unroll
    for (int r = 0; r < 4; ++r) {
      const int qrow = q0 + wave * 16 + g * 4 + r;
      float p = acc[nt][r] * inv[r];
      orow[(long long)qrow * SS + col] = p;
      prow[(long long)qrow * SS + col] = (bf16)p;
    }
  }
}

// ---------------------------------------------------------------------------
// fp32 [K,N] -> bf16 [N,K] transpose-convert (per z matrix)
// ---------------------------------------------------------------------------
__global__ void transpose_cvt(const float* __restrict__ in, bf16* __restrict__ out,
                              int K, int N, long long inZ, long long outZ)
{
  __shared__ float tile[32][33];
  const float* ip = in + (long long)blockIdx.z * inZ;
  bf16* op = out + (long long)blockIdx.z * outZ;
  int n0 = blockIdx.x * 32, k0 = blockIdx.y * 32;
  int tx = threadIdx.x, ty = threadIdx.y;
#pragma unroll
  for (int j = 0; j < 32; j += 8)
    tile[ty + j][tx] = ip[(long long)(k0 + ty + j) * N + n0 + tx];
  __syncthreads();
#pragma unroll
  for (int j = 0; j < 32; j += 8)
    op[(long long)(n0 + ty + j) * K + k0 + tx] = (bf16)tile[tx][ty + j];
}

// bf16 V [B,S,NH*DH] -> Vt [B,NH,DH,S]
__global__ void vtrans(const bf16* __restrict__ v, bf16* __restrict__ vt)
{
  __shared__ bf16 tile[32][33];
  int z = blockIdx.z;                 // b*NH + h
  int b = z / NHD, h = z % NHD;
  int s0 = blockIdx.x * 32, d0 = blockIdx.y * 32;
  int tx = threadIdx.x, ty = threadIdx.y;
  const bf16* ip = v + (long long)b * SS * HD + (long long)h * DH;
#pragma unroll
  for (int j = 0; j < 32; j += 8)
    tile[ty + j][tx] = ip[(long long)(s0 + ty + j) * HD + d0 + tx];
  __syncthreads();
  bf16* op = vt + (long long)z * DH * SS;
#pragma unroll
  for (int j = 0; j < 32; j += 8)
    op[(long long)(d0 + ty + j) * SS + s0 + tx] = tile[tx][ty + j];
}

// pack bq,bk,bv [L,H] -> [L,3,H]
__global__ void pack_bias(const float* __restrict__ bq, const float* __restrict__ bk,
                          const float* __restrict__ bv, float* __restrict__ o)
{
  int i = blockIdx.x * 256 + threadIdx.x;
  if (i >= NL * 3 * HD) return;
  int l = i / (3 * HD);
  int r = i % (3 * HD);
  int sel = r / HD, j = r % HD;
  const float* src = (sel == 0) ? bq : (sel == 1) ? bk : bv;
  o[i] = src[l * HD + j];
}

// x = emb[tok] + pos ; write fp32 + bf16
__global__ void embed_k(const int* __restrict__ tok, const float* __restrict__ emb,
                        const float* __restrict__ pos, float* __restrict__ hf,
                        bf16* __restrict__ hb)
{
  int row = blockIdx.x;               // b*SS + s
  int s = row % SS;
  int tk = tok[row];
  const float* e = emb + (long long)tk * HD;
  const float* p = pos + (long long)s * HD;
#pragma unroll
  for (int j = 0; j < 3; ++j) {
    int c = threadIdx.x + j * 256;
    float v = e[c] + p[c];
    hf[(long long)row * HD + c] = v;
    hb[(long long)row * HD + c] = (bf16)v;
  }
}

// LayerNorm over H=768; writes fp32 dest + bf16 dest
__global__ void ln_k(const float* __restrict__ x, const float* __restrict__ g,
                     const float* __restrict__ be, float* __restrict__ of,
                     bf16* __restrict__ ob)
{
  int row = blockIdx.x;
  const float* xp = x + (long long)row * HD;
  float vals[3];
  float s = 0.f, ss = 0.f;
#pragma unroll
  for (int j = 0; j < 3; ++j) {
    float v = xp[threadIdx.x + j * 256];
    vals[j] = v;
    s += v;
    ss += v * v;
  }
#pragma unroll
  for (int off = 1; off < 64; off <<= 1) {
    s += __shfl_xor(s, off);
    ss += __shfl_xor(ss, off);
  }
  __shared__ float S1[4], S2[4];
  int wave = threadIdx.x >> 6, lane = threadIdx.x & 63;
  if (lane == 0) { S1[wave] = s; S2[wave] = ss; }
  __syncthreads();
  s = S1[0] + S1[1] + S1[2] + S1[3];
  ss = S2[0] + S2[1] + S2[2] + S2[3];
  const float rH = 1.f / (float)HD;
  float mean = s * rH;
  float var = ss * rH - mean * mean;
  float rstd = rsqrtf(var + 1e-12f);
#pragma unroll
  for (int j = 0; j < 3; ++j) {
    int c = threadIdx.x + j * 256;
    float y = (vals[j] - mean) * rstd * g[c] + be[c];
    of[(long long)row * HD + c] = y;
    ob[(long long)row * HD + c] = (bf16)y;
  }
}

// ---------------------------------------------------------------------------
extern "C" void kernel_launch(void* const* d_in, const int* in_sizes, int n_in,
                              void* d_out, int out_size, void* d_ws, size_t ws_size,
                              hipStream_t stream)
{
  (void)in_sizes; (void)n_in; (void)out_size; (void)ws_size;
  const int*   tok = (const int*)  d_in[0];
  const float* emb = (const float*)d_in[1];
  const float* pos = (const float*)d_in[2];
  const float* wq  = (const float*)d_in[3];
  const float* bq  = (const float*)d_in[4];
  const float* wk  = (const float*)d_in[5];
  const float* bk  = (const float*)d_in[6];
  const float* wv  = (const float*)d_in[7];
  const float* bv  = (const float*)d_in[8];
  const float* wo  = (const float*)d_in[9];
  const float* bo  = (const float*)d_in[10];
  const float* g1  = (const float*)d_in[11];
  const float* be1 = (const float*)d_in[12];
  const float* w1  = (const float*)d_in[13];
  const float* b1  = (const float*)d_in[14];
  const float* w2  = (const float*)d_in[15];
  const float* b2  = (const float*)d_in[16];
  const float* g2  = (const float*)d_in[17];
  const float* be2 = (const float*)d_in[18];
  float* out = (float*)d_out;

  // workspace carve-up (~155 MB total)
  char* p = (char*)d_ws;
  auto alloc = [&](size_t bytes) {
    char* r = p;
    p += (bytes + 255) & ~(size_t)255;
    return r;
  };
  const long long HH   = (long long)HD * HD;       // 589824
  const long long WPL  = 4 * HH + 2 * (long long)HD * FF; // 7077888 bf16/layer
  const long long MH   = (long long)BB * SS * HD;  // 1572864
  const long long ATT  = (long long)BB * NHD * SS * SS; // 12582912

  bf16*  WT    = (bf16*) alloc((size_t)(WPL * NL) * 2);
  float* bqkv  = (float*)alloc((size_t)NL * 3 * HD * 4);
  float* hf    = (float*)alloc((size_t)MH * 4);
  float* preln = (float*)alloc((size_t)MH * 4);
  bf16*  hb    = (bf16*) alloc((size_t)MH * 2);
  bf16*  qkvb  = (bf16*) alloc((size_t)3 * MH * 2);
  bf16*  vt    = (bf16*) alloc((size_t)MH * 2);
  bf16*  attnb = (bf16*) alloc((size_t)ATT * 2);
  bf16*  ctxb  = (bf16*) alloc((size_t)MH * 2);
  bf16*  u     = (bf16*) alloc((size_t)BB * SS * FF * 2);

  dim3 tb(32, 8);
  // weights: fp32 [K,N] -> bf16 [N,K] per layer slot
  transpose_cvt<<<dim3(HD/32, HD/32, NL), tb, 0, stream>>>(wq, WT + 0,      HD, HD, HH, WPL);
  transpose_cvt<<<dim3(HD/32, HD/32, NL), tb, 0, stream>>>(wk, WT + HH,     HD, HD, HH, WPL);
  transpose_cvt<<<dim3(HD/32, HD/32, NL), tb, 0, stream>>>(wv, WT + 2*HH,   HD, HD, HH, WPL);
  transpose_cvt<<<dim3(HD/32, HD/32, NL), tb, 0, stream>>>(wo, WT + 3*HH,   HD, HD, HH, WPL);
  transpose_cvt<<<dim3(FF/32, HD/32, NL), tb, 0, stream>>>(w1, WT + 4*HH,   HD, FF, (long long)HD*FF, WPL);
  transpose_cvt<<<dim3(HD/32, FF/32, NL), tb, 0, stream>>>(w2, WT + 4*HH + (long long)HD*FF, FF, HD, (long long)HD*FF, WPL);

  pack_bias<<<dim3((NL * 3 * HD + 255) / 256), 256, 0, stream>>>(bq, bk, bv, bqkv);
  embed_k<<<dim3(BB * SS), 256, 0, stream>>>(tok, emb, pos, hf, hb);

  const long long OUT0 = MH;

  for (int l = 0; l < NL; ++l) {
    const bf16* WQT = WT + (long long)l * WPL;
    const bf16* WKT = WQT + HH;
    const bf16* WVT = WQT + 2 * HH;
    const bf16* WOT = WQT + 3 * HH;
    const bf16* W1T = WQT + 4 * HH;
    const bf16* W2T = WQT + 4 * HH + (long long)HD * FF;
    (void)WKT; (void)WVT;

    // 1. QKV projections (batched z=3 over contiguous Wq/Wk/Wv, bias packed)
    gemm_kernel<128,false><<<dim3(HD/128, (BB*SS)/128, 3), 256, 0, stream>>>(
        hb, WQT, HD, HD, HD, HD, 3,
        0, 0, HH, 0, MH, 0,
        bqkv + (long long)l * 3 * HD, HD, nullptr, 1.f, nullptr, qkvb);

    // 2. V -> Vt [B,NH,DH,S]
    vtrans<<<dim3(SS/32, DH/32, BB*NHD), tb, 0, stream>>>(qkvb + 2 * MH, vt);

    // 3+4. fused scores + mask + softmax -> fp32 P in d_out slice + bf16 P
    attn_fused<<<dim3(SS/64, BB*NHD), 256, 0, stream>>>(
        qkvb, qkvb + MH, tok, out + OUT0 + (long long)l * ATT, attnb);

    // 5. ctx = P @ V  -> bf16 [B,S,H]
    gemm_kernel<64,false><<<dim3(DH/64, SS/128, BB*NHD), 256, 0, stream>>>(
        attnb, vt, SS, SS, SS, HD, NHD,
        (long long)SS*SS, (long long)NHD*SS*SS, (long long)DH*SS, (long long)NHD*DH*SS,
        DH, (long long)SS*HD,
        nullptr, 0, nullptr, 1.f, nullptr, ctxb);

    // 6. O-projection + bias + residual(x)  (BN=64: 192 blocks vs 96)
    gemm_kernel<64,false><<<dim3(HD/64, (BB*SS)/128, 1), 256, 0, stream>>>(
        ctxb, WOT, HD, HD, HD, HD, 1,
        0, 0, 0, 0, 0, 0,
        bo + (long long)l * HD, 0, hf, 1.f, preln, nullptr);

    // 7. LN1 -> hf, hb
    ln_k<<<dim3(BB*SS), 256, 0, stream>>>(preln, g1 + (long long)l*HD, be1 + (long long)l*HD, hf, hb);

    // 8. FFN1 + bias + relu -> u (bf16)
    gemm_kernel<128,true><<<dim3(FF/128, (BB*SS)/128, 1), 256, 0, stream>>>(
        hb, W1T, HD, HD, HD, FF, 1,
        0, 0, 0, 0, 0, 0,
        b1 + (long long)l * FF, 0, nullptr, 1.f, nullptr, u);

    // 9. FFN2 + bias + residual(hf)  (BN=64: 192 blocks vs 96)
    gemm_kernel<64,false><<<dim3(HD/64, (BB*SS)/128, 1), 256, 0, stream>>>(
        u, W2T, FF, FF, FF, HD, 1,
        0, 0, 0, 0, 0, 0,
        b2 + (long long)l * HD, 0, hf, 1.f, preln, nullptr);

    // 10. LN2 -> (hf or final out), hb
    ln_k<<<dim3(BB*SS), 256, 0, stream>>>(preln, g2 + (long long)l*HD, be2 + (long long)l*HD,
                                          (l == NL - 1) ? out : hf, hb);
  }
}

// Round 2
// 1575.699 us; speedup vs baseline: 1.2465x; 1.0422x over previous
//
#include <hip/hip_runtime.h>
#include <stdint.h>

// Problem constants (fixed by reference)
#define VOC 32000
#define HD  768
#define NHD 12
#define DH  64
#define FF  3072
#define NL  6
#define BB  4
#define SS  512

typedef __bf16 bf16;
typedef __attribute__((ext_vector_type(8))) __bf16 bf16x8;
typedef __attribute__((ext_vector_type(4))) __bf16 bf16x4;
typedef __attribute__((ext_vector_type(4))) float f32x4;

// async global->LDS, 16B per lane. LDS dest must be wave-uniform base; HW adds lane*16.
__device__ __forceinline__ void ld_g2l_16(const bf16* g, bf16* lds_base) {
  __builtin_amdgcn_global_load_lds(
      (const __attribute__((address_space(1))) uint32_t*)g,
      (__attribute__((address_space(3))) uint32_t*)lds_base,
      16, 0, 0);
}

static __device__ __forceinline__ unsigned pkbf(float a, float b) {
  union { bf16 h; unsigned short u; } ca, cb;
  ca.h = (bf16)a; cb.h = (bf16)b;
  return (unsigned)ca.u | ((unsigned)cb.u << 16);
}

// ---------------------------------------------------------------------------
// Generic bf16 MFMA GEMM: C[M,N] = alpha * A[M,K] @ Bt[N,K]^T (+bias)(+res)(relu)
// BM=128 fixed, BN in {128,64}. 256 threads = 4 waves (2x2), 16x16x32 bf16 MFMA.
// Batched over blockIdx.z with (inner,outer) strides: z = zo*z_inner + zi.
// outVT: when non-null and zi==2, write transposed bf16 [B,NH,DH,S] instead of outB
// (used by QKV to emit Vt directly, replacing the vtrans kernel).
// ---------------------------------------------------------------------------
template<int BN, bool RELU>
__global__ __launch_bounds__(256)
void gemm_kernel(const bf16* __restrict__ A, const bf16* __restrict__ B,
                 int K, int lda, int ldb, int ldc, int z_inner,
                 long long sAi, long long sAo, long long sBi, long long sBo,
                 long long sCi, long long sCo,
                 const float* __restrict__ bias, int sBias,
                 const float* __restrict__ res, float alpha,
                 float* __restrict__ outF, bf16* __restrict__ outB,
                 bf16* __restrict__ outVT)
{
  constexpr int BM = 128, BK = 32;
  __shared__ bf16 As[BM * BK];
  __shared__ bf16 Bs[BN * BK];

  const int zi = blockIdx.z % z_inner;
  const int zo = blockIdx.z / z_inner;

  const bf16* Ab = A + (long long)zo * sAo + (long long)zi * sAi;
  const bf16* Bb = B + (long long)zo * sBo + (long long)zi * sBi;
  const long long coff = (long long)zo * sCo + (long long)zi * sCi;

  const int m0 = blockIdx.y * BM;
  const int n0 = blockIdx.x * BN;
  const int t = threadIdx.x;
  const int wave = t >> 6;
  const int lane = t & 63;
  const int wm = (wave >> 1) * 64;        // wave row offset in tile
  const int wn = (wave & 1) * (BN / 2);   // wave col offset in tile
  const int lr = lane & 15;               // A-row / B-col / C-col within 16
  const int ko = (lane >> 4) * 8;         // k-octet

  constexpr int NACC = BN / 32;           // 16-col tiles per wave
  f32x4 acc[4][NACC];
  const f32x4 zero4 = {0.f, 0.f, 0.f, 0.f};
#pragma unroll
  for (int i = 0; i < 4; ++i)
#pragma unroll
    for (int j = 0; j < NACC; ++j) acc[i][j] = zero4;

  constexpr int CA = (BM * BK / 8) / 256; // 16B chunks per thread (A)
  constexpr int CB = (BN * BK / 8) / 256; // (B)

  for (int k0 = 0; k0 < K; k0 += BK) {
    __syncthreads();
#pragma unroll
    for (int c = 0; c < CA; ++c) {
      int chunk = c * 256 + t;
      int r = chunk >> 2;
      int kk = (chunk & 3) << 3;
      ld_g2l_16(Ab + (long long)(m0 + r) * lda + (k0 + kk),
                &As[(c * 256 + wave * 64) * 8]);
    }
#pragma unroll
    for (int c = 0; c < CB; ++c) {
      int chunk = c * 256 + t;
      int r = chunk >> 2;
      int kk = (chunk & 3) << 3;
      ld_g2l_16(Bb + (long long)(n0 + r) * ldb + (k0 + kk),
                &Bs[(c * 256 + wave * 64) * 8]);
    }
    __syncthreads();

    bf16x8 af[4];
#pragma unroll
    for (int mi = 0; mi < 4; ++mi)
      af[mi] = *(const bf16x8*)&As[(wm + mi * 16 + lr) * BK + ko];
    bf16x8 bfr[NACC];
#pragma unroll
    for (int ni = 0; ni < NACC; ++ni)
      bfr[ni] = *(const bf16x8*)&Bs[(wn + ni * 16 + lr) * BK + ko];
#pragma unroll
    for (int mi = 0; mi < 4; ++mi)
#pragma unroll
      for (int ni = 0; ni < NACC; ++ni)
        acc[mi][ni] = __builtin_amdgcn_mfma_f32_16x16x32_bf16(
            af[mi], bfr[ni], acc[mi][ni], 0, 0, 0);
  }

  // Epilogue. C/D layout: col = lane&15, row = (lane>>4)*4 + reg  [m89/m91]
  const int r4 = (lane >> 4) * 4;

  if (outVT && zi == 2) {
    // direct Vt write: out[b, h, d, s] from C[row=b*S+s][col=h*64+d]
    // 4 regs (r) = 4 consecutive s for one d -> one 8B bf16x4 store.
#pragma unroll
    for (int ni = 0; ni < NACC; ++ni) {
      const int col = n0 + wn + ni * 16 + lr;
      const int hh = col >> 6, dd = col & 63;
      float bv = bias ? bias[(long long)zi * sBias + col] : 0.f;
#pragma unroll
      for (int mi = 0; mi < 4; ++mi) {
        const int row = m0 + wm + mi * 16 + r4;
        const int bI = row >> 9, sI = row & 511;
        bf16x4 v4;
#pragma unroll
        for (int r = 0; r < 4; ++r) v4[r] = (bf16)(acc[mi][ni][r] * alpha + bv);
        *(bf16x4*)&outVT[(((long long)bI * NHD + hh) * DH + dd) * SS + sI] = v4;
      }
    }
    return;
  }

#pragma unroll
  for (int ni = 0; ni < NACC; ++ni) {
    const int col = n0 + wn + ni * 16 + lr;
    float bv = bias ? bias[(long long)zi * sBias + col] : 0.f;
#pragma unroll
    for (int mi = 0; mi < 4; ++mi) {
#pragma unroll
      for (int r = 0; r < 4; ++r) {
        const int row = m0 + wm + mi * 16 + r4 + r;
        const long long idx = coff + (long long)row * ldc + col;
        float v = acc[mi][ni][r] * alpha + bv;
        if (res) v += res[idx];
        if (RELU) v = fmaxf(v, 0.f);
        if (outF) outF[idx] = v;
        if (outB) outB[idx] = (bf16)v;
      }
    }
  }
}

// ---------------------------------------------------------------------------
// Fully fused attention: scores (S^T via swapped MFMA) + mask + softmax + PV.
// One block = 64 q-rows of one (b,h); 4 waves, each wave owns 16 q-rows.
//
// Phase 1: K [512][64] in LDS (XOR-swizzled 16B granules); S^T = mfma(K, Q):
//   lane (lr,g) holds S[k = nt*16 + g*4 + r][q = q0w + lr] -> each lane owns
//   ONE q-row with 128 k-values; softmax reduce = in-lane + shfl_xor(16,32).
// Phase 2: barrier, issue async Vt [64][512] restage into the SAME LDS
//   (overlaps the softmax VALU work), normalize, write fp32 P (float4),
//   pack P to bf16 pairs in-register.
// Phase 3: PV: A-fragments assembled from packed P via 8 bpermute + 4 selects
//   per k-step (no LDS round-trip); B-fragments = Vt from LDS. ctx -> bf16.
// Removes: softmax kernel, PV GEMM, bf16 P buffer, vtrans consumer traffic.
// ---------------------------------------------------------------------------
__global__ __launch_bounds__(256, 2)
void attn_fused(const bf16* __restrict__ qm, const bf16* __restrict__ km,
                const bf16* __restrict__ vtg, const int* __restrict__ tok,
                float* __restrict__ outP, bf16* __restrict__ ctx)
{
  __shared__ bf16 Ks[SS * DH];            // 64 KB: K, then Vt
  const int z = blockIdx.y;               // b*NH + h
  const int b = z / NHD, h = z - b * NHD;
  const int q0 = blockIdx.x * 64;
  const int t = threadIdx.x;
  const int wave = t >> 6, lane = t & 63;
  const int lr = lane & 15;
  const int g = lane >> 4;
  const int ko = g * 8;

  const bf16* kb = km + (long long)b * SS * HD + h * DH;
  const bf16* qb = qm + ((long long)b * SS + q0) * HD + h * DH;

  // stage K: 512 rows x 8 16B-granules, source-XOR swizzle
#pragma unroll
  for (int c = 0; c < 16; ++c) {
    int chunk = c * 256 + t;
    int r = chunk >> 3;
    int sc = (chunk & 7) ^ (r & 7);
    ld_g2l_16(kb + (long long)r * HD + sc * 8, &Ks[(c * 256 + wave * 64) * 8]);
  }

  // Q fragments: this wave's 16 q-rows (q = q0 + wave*16 + lr)
  const int qr = wave * 16 + lr;
  bf16x8 qf[2];
#pragma unroll
  for (int kk = 0; kk < 2; ++kk)
    qf[kk] = *(const bf16x8*)&qb[(long long)qr * HD + kk * 32 + ko];

  // mask bits for this lane's k's: k = nt*16 + g*4 + r  (bit (nt&7)*4+r of word nt>>3)
  const int* tp = tok + b * SS;
  unsigned mbits[4] = {0u, 0u, 0u, 0u};
#pragma unroll
  for (int nt = 0; nt < 32; ++nt) {
    const int4 t4 = *(const int4*)&tp[nt * 16 + g * 4];
    unsigned bbit = (t4.x == 0 ? 1u : 0u) | (t4.y == 0 ? 2u : 0u) |
                    (t4.z == 0 ? 4u : 0u) | (t4.w == 0 ? 8u : 0u);
    mbits[nt >> 3] |= bbit << ((nt & 7) * 4);
  }

  __syncthreads();

  // S^T = K @ Q^T : acc[nt] holds rows k = nt*16+g*4+r, col q = lr
  f32x4 acc[32];
  const f32x4 zero4 = {0.f, 0.f, 0.f, 0.f};
#pragma unroll
  for (int nt = 0; nt < 32; ++nt) acc[nt] = zero4;

#pragma unroll
  for (int nt = 0; nt < 32; ++nt) {
    const int kr = nt * 16 + lr;
#pragma unroll
    for (int kk = 0; kk < 2; ++kk) {
      const int gran = (kk * 4 + g) ^ (kr & 7);
      bf16x8 kf = *(const bf16x8*)&Ks[kr * DH + gran * 8];
      acc[nt] = __builtin_amdgcn_mfma_f32_16x16x32_bf16(kf, qf[kk], acc[nt], 0, 0, 0);
    }
  }

  __syncthreads();  // all waves done reading K

  // issue async Vt restage NOW; latency hides under softmax VALU below
  const bf16* vb = vtg + (long long)z * DH * SS;
#pragma unroll
  for (int c = 0; c < 16; ++c) {
    int chunk = c * 256 + t;            // 64 rows x 64 granules
    int r = chunk >> 6;
    int gr = chunk & 63;
    int sg = gr ^ (r & 7);
    ld_g2l_16(vb + (long long)r * SS + sg * 8, &Ks[(c * 256 + wave * 64) * 8]);
  }

  // scale + mask (ref-exact: + -10000 on masked cols), row max
  float mx = -1e30f;
#pragma unroll
  for (int nt = 0; nt < 32; ++nt)
#pragma unroll
    for (int r = 0; r < 4; ++r) {
      float v = acc[nt][r] * 0.125f;
      unsigned bit = (mbits[nt >> 3] >> ((nt & 7) * 4 + r)) & 1u;
      v += bit ? -10000.f : 0.f;
      acc[nt][r] = v;
      mx = fmaxf(mx, v);
    }
  mx = fmaxf(mx, __shfl_xor(mx, 16));
  mx = fmaxf(mx, __shfl_xor(mx, 32));

  float sum = 0.f;
#pragma unroll
  for (int nt = 0; nt < 32; ++nt)
#pragma unroll
    for (int r = 0; r < 4; ++r) {
      float p = __expf(acc[nt][r] - mx);
      acc[nt][r] = p;
      sum += p;
    }
  sum += __shfl_xor(sum, 16);
  sum += __shfl_xor(sum, 32);
  const float inv = 1.f / sum;

  // normalize, write fp32 P (required output), pack bf16 pairs
  float* orow = outP + (long long)z * SS * SS
              + (long long)(q0 + wave * 16 + lr) * SS + g * 4;
  unsigned pk[64];
#pragma unroll
  for (int nt = 0; nt < 32; ++nt) {
    f32x4 pv;
#pragma unroll
    for (int r = 0; r < 4; ++r) pv[r] = acc[nt][r] * inv;
    *(f32x4*)(orow + nt * 16) = pv;
    pk[nt * 2]     = pkbf(pv[0], pv[1]);
    pk[nt * 2 + 1] = pkbf(pv[2], pv[3]);
  }

  // PV: ctx[q][d], A = P assembled in-register, B = Vt from LDS
  f32x4 ctxa[4];
#pragma unroll
  for (int dt = 0; dt < 4; ++dt) ctxa[dt] = zero4;

  const int s0 = lr + ((g & 1) ? 32 : 0);
  const int s1 = s0 + 16;

  __syncthreads();  // Vt staged (syncthreads drains vmcnt)

#pragma unroll
  for (int ks = 0; ks < 16; ++ks) {
    const int nt0 = 2 * ks, nt1 = nt0 + 1;
    unsigned w0 = (unsigned)__shfl((int)pk[nt0 * 2],     s0);
    unsigned w1 = (unsigned)__shfl((int)pk[nt0 * 2 + 1], s0);
    unsigned w2 = (unsigned)__shfl((int)pk[nt0 * 2],     s1);
    unsigned w3 = (unsigned)__shfl((int)pk[nt0 * 2 + 1], s1);
    unsigned x0 = (unsigned)__shfl((int)pk[nt1 * 2],     s0);
    unsigned x1 = (unsigned)__shfl((int)pk[nt1 * 2 + 1], s0);
    unsigned x2 = (unsigned)__shfl((int)pk[nt1 * 2],     s1);
    unsigned x3 = (unsigned)__shfl((int)pk[nt1 * 2 + 1], s1);
    union { unsigned u[4]; bf16x8 v; } au;
    au.u[0] = (g < 2) ? w0 : x0;
    au.u[1] = (g < 2) ? w1 : x1;
    au.u[2] = (g < 2) ? w2 : x2;
    au.u[3] = (g < 2) ? w3 : x3;
#pragma unroll
    for (int dt = 0; dt < 4; ++dt) {
      const int dr = dt * 16 + lr;
      const int gran = (ks * 4 + g) ^ (dr & 7);
      bf16x8 bfv = *(const bf16x8*)&Ks[dr * SS + gran * 8];
      ctxa[dt] = __builtin_amdgcn_mfma_f32_16x16x32_bf16(au.v, bfv, ctxa[dt], 0, 0, 0);
    }
  }

  // ctx write: D[q=g*4+r][d=dt*16+lr] -> ctx[b, q0+wave*16+q, h*64+d] bf16
  bf16* cb = ctx + ((long long)b * SS + q0 + wave * 16) * HD + h * DH;
#pragma unroll
  for (int dt = 0; dt < 4; ++dt)
#pragma unroll
    for (int r = 0; r < 4; ++r)
      cb[(long long)(g * 4 + r) * HD + dt * 16 + lr] = (bf16)ctxa[dt][r];
}

// ---------------------------------------------------------------------------
// fp32 [K,N] -> bf16 [N,K] transpose-convert (per z matrix)
// ---------------------------------------------------------------------------
__global__ void transpose_cvt(const float* __restrict__ in, bf16* __restrict__ out,
                              int K, int N, long long inZ, long long outZ)
{
  __shared__ float tile[32][33];
  const float* ip = in + (long long)blockIdx.z * inZ;
  bf16* op = out + (long long)blockIdx.z * outZ;
  int n0 = blockIdx.x * 32, k0 = blockIdx.y * 32;
  int tx = threadIdx.x, ty = threadIdx.y;
#pragma unroll
  for (int j = 0; j < 32; j += 8)
    tile[ty + j][tx] = ip[(long long)(k0 + ty + j) * N + n0 + tx];
  __syncthreads();
#pragma unroll
  for (int j = 0; j < 32; j += 8)
    op[(long long)(n0 + ty + j) * K + k0 + tx] = (bf16)tile[tx][ty + j];
}

// pack bq,bk,bv [L,H] -> [L,3,H]
__global__ void pack_bias(const float* __restrict__ bq, const float* __restrict__ bk,
                          const float* __restrict__ bv, float* __restrict__ o)
{
  int i = blockIdx.x * 256 + threadIdx.x;
  if (i >= NL * 3 * HD) return;
  int l = i / (3 * HD);
  int r = i % (3 * HD);
  int sel = r / HD, j = r % HD;
  const float* src = (sel == 0) ? bq : (sel == 1) ? bk : bv;
  o[i] = src[l * HD + j];
}

// x = emb[tok] + pos ; write fp32 + bf16
__global__ void embed_k(const int* __restrict__ tok, const float* __restrict__ emb,
                        const float* __restrict__ pos, float* __restrict__ hf,
                        bf16* __restrict__ hb)
{
  int row = blockIdx.x;               // b*SS + s
  int s = row % SS;
  int tk = tok[row];
  const float* e = emb + (long long)tk * HD;
  const float* p = pos + (long long)s * HD;
#pragma unroll
  for (int j = 0; j < 3; ++j) {
    int c = threadIdx.x + j * 256;
    float v = e[c] + p[c];
    hf[(long long)row * HD + c] = v;
    hb[(long long)row * HD + c] = (bf16)v;
  }
}

// LayerNorm over H=768; writes fp32 dest + bf16 dest
__global__ void ln_k(const float* __restrict__ x, const float* __restrict__ g,
                     const float* __restrict__ be, float* __restrict__ of,
                     bf16* __restrict__ ob)
{
  int row = blockIdx.x;
  const float* xp = x + (long long)row * HD;
  float vals[3];
  float s = 0.f, ss = 0.f;
#pragma unroll
  for (int j = 0; j < 3; ++j) {
    float v = xp[threadIdx.x + j * 256];
    vals[j] = v;
    s += v;
    ss += v * v;
  }
#pragma unroll
  for (int off = 1; off < 64; off <<= 1) {
    s += __shfl_xor(s, off);
    ss += __shfl_xor(ss, off);
  }
  __shared__ float S1[4], S2[4];
  int wave = threadIdx.x >> 6, lane = threadIdx.x & 63;
  if (lane == 0) { S1[wave] = s; S2[wave] = ss; }
  __syncthreads();
  s = S1[0] + S1[1] + S1[2] + S1[3];
  ss = S2[0] + S2[1] + S2[2] + S2[3];
  const float rH = 1.f / (float)HD;
  float mean = s * rH;
  float var = ss * rH - mean * mean;
  float rstd = rsqrtf(var + 1e-12f);
#pragma unroll
  for (int j = 0; j < 3; ++j) {
    int c = threadIdx.x + j * 256;
    float y = (vals[j] - mean) * rstd * g[c] + be[c];
    of[(long long)row * HD + c] = y;
    ob[(long long)row * HD + c] = (bf16)y;
  }
}

// ---------------------------------------------------------------------------
extern "C" void kernel_launch(void* const* d_in, const int* in_sizes, int n_in,
                              void* d_out, int out_size, void* d_ws, size_t ws_size,
                              hipStream_t stream)
{
  (void)in_sizes; (void)n_in; (void)out_size; (void)ws_size;
  const int*   tok = (const int*)  d_in[0];
  const float* emb = (const float*)d_in[1];
  const float* pos = (const float*)d_in[2];
  const float* wq  = (const float*)d_in[3];
  const float* bq  = (const float*)d_in[4];
  const float* wk  = (const float*)d_in[5];
  const float* bk  = (const float*)d_in[6];
  const float* wv  = (const float*)d_in[7];
  const float* bv  = (const float*)d_in[8];
  const float* wo  = (const float*)d_in[9];
  const float* bo  = (const float*)d_in[10];
  const float* g1  = (const float*)d_in[11];
  const float* be1 = (const float*)d_in[12];
  const float* w1  = (const float*)d_in[13];
  const float* b1  = (const float*)d_in[14];
  const float* w2  = (const float*)d_in[15];
  const float* b2  = (const float*)d_in[16];
  const float* g2  = (const float*)d_in[17];
  const float* be2 = (const float*)d_in[18];
  float* out = (float*)d_out;

  // workspace carve-up
  char* p = (char*)d_ws;
  auto alloc = [&](size_t bytes) {
    char* r = p;
    p += (bytes + 255) & ~(size_t)255;
    return r;
  };
  const long long HH   = (long long)HD * HD;       // 589824
  const long long WPL  = 4 * HH + 2 * (long long)HD * FF; // 7077888 bf16/layer
  const long long MH   = (long long)BB * SS * HD;  // 1572864
  const long long ATT  = (long long)BB * NHD * SS * SS; // 12582912

  bf16*  WT    = (bf16*) alloc((size_t)(WPL * NL) * 2);
  float* bqkv  = (float*)alloc((size_t)NL * 3 * HD * 4);
  float* hf    = (float*)alloc((size_t)MH * 4);
  float* preln = (float*)alloc((size_t)MH * 4);
  bf16*  hb    = (bf16*) alloc((size_t)MH * 2);
  bf16*  qkvb  = (bf16*) alloc((size_t)3 * MH * 2);
  bf16*  vt    = (bf16*) alloc((size_t)MH * 2);
  bf16*  ctxb  = (bf16*) alloc((size_t)MH * 2);
  bf16*  u     = (bf16*) alloc((size_t)BB * SS * FF * 2);

  dim3 tb(32, 8);
  // weights: fp32 [K,N] -> bf16 [N,K] per layer slot
  transpose_cvt<<<dim3(HD/32, HD/32, NL), tb, 0, stream>>>(wq, WT + 0,      HD, HD, HH, WPL);
  transpose_cvt<<<dim3(HD/32, HD/32, NL), tb, 0, stream>>>(wk, WT + HH,     HD, HD, HH, WPL);
  transpose_cvt<<<dim3(HD/32, HD/32, NL), tb, 0, stream>>>(wv, WT + 2*HH,   HD, HD, HH, WPL);
  transpose_cvt<<<dim3(HD/32, HD/32, NL), tb, 0, stream>>>(wo, WT + 3*HH,   HD, HD, HH, WPL);
  transpose_cvt<<<dim3(FF/32, HD/32, NL), tb, 0, stream>>>(w1, WT + 4*HH,   HD, FF, (long long)HD*FF, WPL);
  transpose_cvt<<<dim3(HD/32, FF/32, NL), tb, 0, stream>>>(w2, WT + 4*HH + (long long)HD*FF, FF, HD, (long long)HD*FF, WPL);

  pack_bias<<<dim3((NL * 3 * HD + 255) / 256), 256, 0, stream>>>(bq, bk, bv, bqkv);
  embed_k<<<dim3(BB * SS), 256, 0, stream>>>(tok, emb, pos, hf, hb);

  const long long OUT0 = MH;

  for (int l = 0; l < NL; ++l) {
    const bf16* WQT = WT + (long long)l * WPL;
    const bf16* WOT = WQT + 3 * HH;
    const bf16* W1T = WQT + 4 * HH;
    const bf16* W2T = WQT + 4 * HH + (long long)HD * FF;

    // 1. QKV projections (z=3); zi==2 (V) writes Vt directly
    gemm_kernel<128,false><<<dim3(HD/128, (BB*SS)/128, 3), 256, 0, stream>>>(
        hb, WQT, HD, HD, HD, HD, 3,
        0, 0, HH, 0, MH, 0,
        bqkv + (long long)l * 3 * HD, HD, nullptr, 1.f, nullptr, qkvb, vt);

    // 2. fused scores + mask + softmax + PV -> fp32 P (d_out slice) + ctx bf16
    attn_fused<<<dim3(SS/64, BB*NHD), 256, 0, stream>>>(
        qkvb, qkvb + MH, vt, tok, out + OUT0 + (long long)l * ATT, ctxb);

    // 3. O-projection + bias + residual(x)
    gemm_kernel<64,false><<<dim3(HD/64, (BB*SS)/128, 1), 256, 0, stream>>>(
        ctxb, WOT, HD, HD, HD, HD, 1,
        0, 0, 0, 0, 0, 0,
        bo + (long long)l * HD, 0, hf, 1.f, preln, nullptr, nullptr);

    // 4. LN1 -> hf, hb
    ln_k<<<dim3(BB*SS), 256, 0, stream>>>(preln, g1 + (long long)l*HD, be1 + (long long)l*HD, hf, hb);

    // 5. FFN1 + bias + relu -> u (bf16)
    gemm_kernel<128,true><<<dim3(FF/128, (BB*SS)/128, 1), 256, 0, stream>>>(
        hb, W1T, HD, HD, HD, FF, 1,
        0, 0, 0, 0, 0, 0,
        b1 + (long long)l * FF, 0, nullptr, 1.f, nullptr, u, nullptr);

    // 6. FFN2 + bias + residual(hf)
    gemm_kernel<64,false><<<dim3(HD/64, (BB*SS)/128, 1), 256, 0, stream>>>(
        u, W2T, FF, FF, FF, HD, 1,
        0, 0, 0, 0, 0, 0,
        b2 + (long long)l * HD, 0, hf, 1.f, preln, nullptr, nullptr);

    // 7. LN2 -> (hf or final out), hb
    ln_k<<<dim3(BB*SS), 256, 0, stream>>>(preln, g2 + (long long)l*HD, be2 + (long long)l*HD,
                                          (l == NL - 1) ? out : hf, hb);
  }
}

// Round 3
// 1257.365 us; speedup vs baseline: 1.5621x; 1.2532x over previous
//
#include <hip/hip_runtime.h>
#include <stdint.h>

// Problem constants (fixed by reference)
#define VOC 32000
#define HD  768
#define NHD 12
#define DH  64
#define FF  3072
#define NL  6
#define BB  4
#define SS  512

typedef __bf16 bf16;
typedef __attribute__((ext_vector_type(8))) __bf16 bf16x8;
typedef __attribute__((ext_vector_type(4))) __bf16 bf16x4;
typedef __attribute__((ext_vector_type(4))) float f32x4;

// async global->LDS, 16B per lane. LDS dest must be wave-uniform base; HW adds lane*16.
__device__ __forceinline__ void ld_g2l_16(const bf16* g, bf16* lds_base) {
  __builtin_amdgcn_global_load_lds(
      (const __attribute__((address_space(1))) uint32_t*)g,
      (__attribute__((address_space(3))) uint32_t*)lds_base,
      16, 0, 0);
}

static __device__ __forceinline__ unsigned pkbf(float a, float b) {
  union { bf16 h; unsigned short u; } ca, cb;
  ca.h = (bf16)a; cb.h = (bf16)b;
  return (unsigned)ca.u | ((unsigned)cb.u << 16);
}

// ---------------------------------------------------------------------------
// bf16 MFMA GEMM: C[M,N] = alpha * A[M,K] @ Bt[N,K]^T (+bias)(+res)(relu)
// BM,BN in {64,128}. 256 threads = 4 waves (2x2); wave tile (BM/2)x(BN/2).
// BK=64, double-buffered LDS (one barrier per k-step, staging overlaps MFMA),
// XOR-granule swizzle (both sides: pre-swizzled global source + swizzled
// ds_read) -> conflict-free ds_read_b128.
// Batched over blockIdx.z with (inner,outer) strides: z = zo*z_inner + zi.
// outVT: when non-null and zi==2, write transposed bf16 [B,NH,DH,S] (Vt).
// ---------------------------------------------------------------------------
template<int BM, int BN, bool RELU>
__global__ __launch_bounds__(256)
void gemm_kernel(const bf16* __restrict__ A, const bf16* __restrict__ B,
                 int K, int lda, int ldb, int ldc, int z_inner,
                 long long sAi, long long sAo, long long sBi, long long sBo,
                 long long sCi, long long sCo,
                 const float* __restrict__ bias, int sBias,
                 const float* __restrict__ res, float alpha,
                 float* __restrict__ outF, bf16* __restrict__ outB,
                 bf16* __restrict__ outVT)
{
  constexpr int BK = 64;                  // 8 granules of 16B per row
  __shared__ bf16 As[2][BM * BK];
  __shared__ bf16 Bs[2][BN * BK];

  const int zi = blockIdx.z % z_inner;
  const int zo = blockIdx.z / z_inner;

  const bf16* Ab = A + (long long)zo * sAo + (long long)zi * sAi;
  const bf16* Bb = B + (long long)zo * sBo + (long long)zi * sBi;
  const long long coff = (long long)zo * sCo + (long long)zi * sCi;

  const int m0 = blockIdx.y * BM;
  const int n0 = blockIdx.x * BN;
  const int t = threadIdx.x;
  const int wave = t >> 6;
  const int lane = t & 63;
  const int wm = (wave >> 1) * (BM / 2);
  const int wn = (wave & 1) * (BN / 2);
  const int lr = lane & 15;               // row-within-16 selector
  const int g = lane >> 4;                // k-granule selector (0..3)

  constexpr int MI = BM / 32;             // 16-row frags per wave (m)
  constexpr int NI = BN / 32;             // 16-col frags per wave (n)
  f32x4 acc[MI][NI];
  const f32x4 zero4 = {0.f, 0.f, 0.f, 0.f};
#pragma unroll
  for (int i = 0; i < MI; ++i)
#pragma unroll
    for (int j = 0; j < NI; ++j) acc[i][j] = zero4;

  constexpr int CA = (BM * BK / 8) / 256; // 16B chunks per thread (A)
  constexpr int CB = (BN * BK / 8) / 256; // (B)

  // stage one BK-tile into buffer sel; source address pre-swizzled so that
  // LDS granule gc of row r holds global granule gc^(r&7).
  auto stage = [&](int sel, int k0) {
#pragma unroll
    for (int c = 0; c < CA; ++c) {
      int chunk = c * 256 + t;
      int r = chunk >> 3;
      int sg = (chunk & 7) ^ (r & 7);
      ld_g2l_16(Ab + (long long)(m0 + r) * lda + (k0 + sg * 8),
                &As[sel][(c * 256 + wave * 64) * 8]);
    }
#pragma unroll
    for (int c = 0; c < CB; ++c) {
      int chunk = c * 256 + t;
      int r = chunk >> 3;
      int sg = (chunk & 7) ^ (r & 7);
      ld_g2l_16(Bb + (long long)(n0 + r) * ldb + (k0 + sg * 8),
                &Bs[sel][(c * 256 + wave * 64) * 8]);
    }
  };

  stage(0, 0);
  __syncthreads();

  const int NS = K / BK;
  for (int s = 0; s < NS; ++s) {
    const int cur = s & 1;
    // ds_read current buffer (swizzled granule addressing)
    bf16x8 af[2][MI], bfr[2][NI];
#pragma unroll
    for (int kk = 0; kk < 2; ++kk) {
#pragma unroll
      for (int mi = 0; mi < MI; ++mi) {
        const int row = wm + mi * 16 + lr;
        af[kk][mi] = *(const bf16x8*)&As[cur][row * BK + (((kk * 4 + g) ^ (row & 7)) * 8)];
      }
#pragma unroll
      for (int ni = 0; ni < NI; ++ni) {
        const int row = wn + ni * 16 + lr;
        bfr[kk][ni] = *(const bf16x8*)&Bs[cur][row * BK + (((kk * 4 + g) ^ (row & 7)) * 8)];
      }
    }
    // issue next tile's loads into the other buffer (overlaps MFMA below)
    if (s + 1 < NS) stage(cur ^ 1, (s + 1) * BK);
    // MFMA
#pragma unroll
    for (int kk = 0; kk < 2; ++kk)
#pragma unroll
      for (int mi = 0; mi < MI; ++mi)
#pragma unroll
        for (int ni = 0; ni < NI; ++ni)
          acc[mi][ni] = __builtin_amdgcn_mfma_f32_16x16x32_bf16(
              af[kk][mi], bfr[kk][ni], acc[mi][ni], 0, 0, 0);
    __syncthreads();   // drains vmcnt (next-tile loads) + barrier
  }

  // Epilogue. C/D layout: col = lane&15, row = (lane>>4)*4 + reg  [m89/m91]
  const int r4 = (lane >> 4) * 4;

  if (outVT && zi == 2) {
    // direct Vt write: out[b, h, d, s] from C[row=b*S+s][col=h*64+d]
#pragma unroll
    for (int ni = 0; ni < NI; ++ni) {
      const int col = n0 + wn + ni * 16 + lr;
      const int hh = col >> 6, dd = col & 63;
      float bv = bias ? bias[(long long)zi * sBias + col] : 0.f;
#pragma unroll
      for (int mi = 0; mi < MI; ++mi) {
        const int row = m0 + wm + mi * 16 + r4;
        const int bI = row >> 9, sI = row & 511;
        bf16x4 v4;
#pragma unroll
        for (int r = 0; r < 4; ++r) v4[r] = (bf16)(acc[mi][ni][r] * alpha + bv);
        *(bf16x4*)&outVT[(((long long)bI * NHD + hh) * DH + dd) * SS + sI] = v4;
      }
    }
    return;
  }

#pragma unroll
  for (int ni = 0; ni < NI; ++ni) {
    const int col = n0 + wn + ni * 16 + lr;
    float bv = bias ? bias[(long long)zi * sBias + col] : 0.f;
#pragma unroll
    for (int mi = 0; mi < MI; ++mi) {
#pragma unroll
      for (int r = 0; r < 4; ++r) {
        const int row = m0 + wm + mi * 16 + r4 + r;
        const long long idx = coff + (long long)row * ldc + col;
        float v = acc[mi][ni][r] * alpha + bv;
        if (res) v += res[idx];
        if (RELU) v = fmaxf(v, 0.f);
        if (outF) outF[idx] = v;
        if (outB) outB[idx] = (bf16)v;
      }
    }
  }
}

// ---------------------------------------------------------------------------
// Fully fused attention: scores (S^T via swapped MFMA) + mask + softmax + PV.
// (unchanged from R2 — see comments there)
// ---------------------------------------------------------------------------
__global__ __launch_bounds__(256, 2)
void attn_fused(const bf16* __restrict__ qm, const bf16* __restrict__ km,
                const bf16* __restrict__ vtg, const int* __restrict__ tok,
                float* __restrict__ outP, bf16* __restrict__ ctx)
{
  __shared__ bf16 Ks[SS * DH];            // 64 KB: K, then Vt
  const int z = blockIdx.y;               // b*NH + h
  const int b = z / NHD, h = z - b * NHD;
  const int q0 = blockIdx.x * 64;
  const int t = threadIdx.x;
  const int wave = t >> 6, lane = t & 63;
  const int lr = lane & 15;
  const int g = lane >> 4;
  const int ko = g * 8;

  const bf16* kb = km + (long long)b * SS * HD + h * DH;
  const bf16* qb = qm + ((long long)b * SS + q0) * HD + h * DH;

  // stage K: 512 rows x 8 16B-granules, source-XOR swizzle
#pragma unroll
  for (int c = 0; c < 16; ++c) {
    int chunk = c * 256 + t;
    int r = chunk >> 3;
    int sc = (chunk & 7) ^ (r & 7);
    ld_g2l_16(kb + (long long)r * HD + sc * 8, &Ks[(c * 256 + wave * 64) * 8]);
  }

  // Q fragments: this wave's 16 q-rows (q = q0 + wave*16 + lr)
  const int qr = wave * 16 + lr;
  bf16x8 qf[2];
#pragma unroll
  for (int kk = 0; kk < 2; ++kk)
    qf[kk] = *(const bf16x8*)&qb[(long long)qr * HD + kk * 32 + ko];

  // mask bits for this lane's k's: k = nt*16 + g*4 + r
  const int* tp = tok + b * SS;
  unsigned mbits[4] = {0u, 0u, 0u, 0u};
#pragma unroll
  for (int nt = 0; nt < 32; ++nt) {
    const int4 t4 = *(const int4*)&tp[nt * 16 + g * 4];
    unsigned bbit = (t4.x == 0 ? 1u : 0u) | (t4.y == 0 ? 2u : 0u) |
                    (t4.z == 0 ? 4u : 0u) | (t4.w == 0 ? 8u : 0u);
    mbits[nt >> 3] |= bbit << ((nt & 7) * 4);
  }

  __syncthreads();

  // S^T = K @ Q^T : acc[nt] holds rows k = nt*16+g*4+r, col q = lr
  f32x4 acc[32];
  const f32x4 zero4 = {0.f, 0.f, 0.f, 0.f};
#pragma unroll
  for (int nt = 0; nt < 32; ++nt) acc[nt] = zero4;

#pragma unroll
  for (int nt = 0; nt < 32; ++nt) {
    const int kr = nt * 16 + lr;
#pragma unroll
    for (int kk = 0; kk < 2; ++kk) {
      const int gran = (kk * 4 + g) ^ (kr & 7);
      bf16x8 kf = *(const bf16x8*)&Ks[kr * DH + gran * 8];
      acc[nt] = __builtin_amdgcn_mfma_f32_16x16x32_bf16(kf, qf[kk], acc[nt], 0, 0, 0);
    }
  }

  __syncthreads();  // all waves done reading K

  // issue async Vt restage NOW; latency hides under softmax VALU below
  const bf16* vb = vtg + (long long)z * DH * SS;
#pragma unroll
  for (int c = 0; c < 16; ++c) {
    int chunk = c * 256 + t;            // 64 rows x 64 granules
    int r = chunk >> 6;
    int gr = chunk & 63;
    int sg = gr ^ (r & 7);
    ld_g2l_16(vb + (long long)r * SS + sg * 8, &Ks[(c * 256 + wave * 64) * 8]);
  }

  // scale + mask (ref-exact: + -10000 on masked cols), row max
  float mx = -1e30f;
#pragma unroll
  for (int nt = 0; nt < 32; ++nt)
#pragma unroll
    for (int r = 0; r < 4; ++r) {
      float v = acc[nt][r] * 0.125f;
      unsigned bit = (mbits[nt >> 3] >> ((nt & 7) * 4 + r)) & 1u;
      v += bit ? -10000.f : 0.f;
      acc[nt][r] = v;
      mx = fmaxf(mx, v);
    }
  mx = fmaxf(mx, __shfl_xor(mx, 16));
  mx = fmaxf(mx, __shfl_xor(mx, 32));

  float sum = 0.f;
#pragma unroll
  for (int nt = 0; nt < 32; ++nt)
#pragma unroll
    for (int r = 0; r < 4; ++r) {
      float p = __expf(acc[nt][r] - mx);
      acc[nt][r] = p;
      sum += p;
    }
  sum += __shfl_xor(sum, 16);
  sum += __shfl_xor(sum, 32);
  const float inv = 1.f / sum;

  // normalize, write fp32 P (required output), pack bf16 pairs
  float* orow = outP + (long long)z * SS * SS
              + (long long)(q0 + wave * 16 + lr) * SS + g * 4;
  unsigned pk[64];
#pragma unroll
  for (int nt = 0; nt < 32; ++nt) {
    f32x4 pv;
#pragma unroll
    for (int r = 0; r < 4; ++r) pv[r] = acc[nt][r] * inv;
    *(f32x4*)(orow + nt * 16) = pv;
    pk[nt * 2]     = pkbf(pv[0], pv[1]);
    pk[nt * 2 + 1] = pkbf(pv[2], pv[3]);
  }

  // PV: ctx[q][d], A = P assembled in-register, B = Vt from LDS
  f32x4 ctxa[4];
#pragma unroll
  for (int dt = 0; dt < 4; ++dt) ctxa[dt] = zero4;

  const int s0 = lr + ((g & 1) ? 32 : 0);
  const int s1 = s0 + 16;

  __syncthreads();  // Vt staged (syncthreads drains vmcnt)

#pragma unroll
  for (int ks = 0; ks < 16; ++ks) {
    const int nt0 = 2 * ks, nt1 = nt0 + 1;
    unsigned w0 = (unsigned)__shfl((int)pk[nt0 * 2],     s0);
    unsigned w1 = (unsigned)__shfl((int)pk[nt0 * 2 + 1], s0);
    unsigned w2 = (unsigned)__shfl((int)pk[nt0 * 2],     s1);
    unsigned w3 = (unsigned)__shfl((int)pk[nt0 * 2 + 1], s1);
    unsigned x0 = (unsigned)__shfl((int)pk[nt1 * 2],     s0);
    unsigned x1 = (unsigned)__shfl((int)pk[nt1 * 2 + 1], s0);
    unsigned x2 = (unsigned)__shfl((int)pk[nt1 * 2],     s1);
    unsigned x3 = (unsigned)__shfl((int)pk[nt1 * 2 + 1], s1);
    union { unsigned u[4]; bf16x8 v; } au;
    au.u[0] = (g < 2) ? w0 : x0;
    au.u[1] = (g < 2) ? w1 : x1;
    au.u[2] = (g < 2) ? w2 : x2;
    au.u[3] = (g < 2) ? w3 : x3;
#pragma unroll
    for (int dt = 0; dt < 4; ++dt) {
      const int dr = dt * 16 + lr;
      const int gran = (ks * 4 + g) ^ (dr & 7);
      bf16x8 bfv = *(const bf16x8*)&Ks[dr * SS + gran * 8];
      ctxa[dt] = __builtin_amdgcn_mfma_f32_16x16x32_bf16(au.v, bfv, ctxa[dt], 0, 0, 0);
    }
  }

  // ctx write: D[q=g*4+r][d=dt*16+lr] -> ctx[b, q0+wave*16+q, h*64+d] bf16
  bf16* cb = ctx + ((long long)b * SS + q0 + wave * 16) * HD + h * DH;
#pragma unroll
  for (int dt = 0; dt < 4; ++dt)
#pragma unroll
    for (int r = 0; r < 4; ++r)
      cb[(long long)(g * 4 + r) * HD + dt * 16 + lr] = (bf16)ctxa[dt][r];
}

// ---------------------------------------------------------------------------
// fp32 [K,N] -> bf16 [N,K] transpose-convert (per z matrix)
// ---------------------------------------------------------------------------
__global__ void transpose_cvt(const float* __restrict__ in, bf16* __restrict__ out,
                              int K, int N, long long inZ, long long outZ)
{
  __shared__ float tile[32][33];
  const float* ip = in + (long long)blockIdx.z * inZ;
  bf16* op = out + (long long)blockIdx.z * outZ;
  int n0 = blockIdx.x * 32, k0 = blockIdx.y * 32;
  int tx = threadIdx.x, ty = threadIdx.y;
#pragma unroll
  for (int j = 0; j < 32; j += 8)
    tile[ty + j][tx] = ip[(long long)(k0 + ty + j) * N + n0 + tx];
  __syncthreads();
#pragma unroll
  for (int j = 0; j < 32; j += 8)
    op[(long long)(n0 + ty + j) * K + k0 + tx] = (bf16)tile[tx][ty + j];
}

// pack bq,bk,bv [L,H] -> [L,3,H]
__global__ void pack_bias(const float* __restrict__ bq, const float* __restrict__ bk,
                          const float* __restrict__ bv, float* __restrict__ o)
{
  int i = blockIdx.x * 256 + threadIdx.x;
  if (i >= NL * 3 * HD) return;
  int l = i / (3 * HD);
  int r = i % (3 * HD);
  int sel = r / HD, j = r % HD;
  const float* src = (sel == 0) ? bq : (sel == 1) ? bk : bv;
  o[i] = src[l * HD + j];
}

// x = emb[tok] + pos ; write fp32 + bf16
__global__ void embed_k(const int* __restrict__ tok, const float* __restrict__ emb,
                        const float* __restrict__ pos, float* __restrict__ hf,
                        bf16* __restrict__ hb)
{
  int row = blockIdx.x;               // b*SS + s
  int s = row % SS;
  int tk = tok[row];
  const float* e = emb + (long long)tk * HD;
  const float* p = pos + (long long)s * HD;
#pragma unroll
  for (int j = 0; j < 3; ++j) {
    int c = threadIdx.x + j * 256;
    float v = e[c] + p[c];
    hf[(long long)row * HD + c] = v;
    hb[(long long)row * HD + c] = (bf16)v;
  }
}

// LayerNorm over H=768; writes fp32 dest + bf16 dest
__global__ void ln_k(const float* __restrict__ x, const float* __restrict__ g,
                     const float* __restrict__ be, float* __restrict__ of,
                     bf16* __restrict__ ob)
{
  int row = blockIdx.x;
  const float* xp = x + (long long)row * HD;
  float vals[3];
  float s = 0.f, ss = 0.f;
#pragma unroll
  for (int j = 0; j < 3; ++j) {
    float v = xp[threadIdx.x + j * 256];
    vals[j] = v;
    s += v;
    ss += v * v;
  }
#pragma unroll
  for (int off = 1; off < 64; off <<= 1) {
    s += __shfl_xor(s, off);
    ss += __shfl_xor(ss, off);
  }
  __shared__ float S1[4], S2[4];
  int wave = threadIdx.x >> 6, lane = threadIdx.x & 63;
  if (lane == 0) { S1[wave] = s; S2[wave] = ss; }
  __syncthreads();
  s = S1[0] + S1[1] + S1[2] + S1[3];
  ss = S2[0] + S2[1] + S2[2] + S2[3];
  const float rH = 1.f / (float)HD;
  float mean = s * rH;
  float var = ss * rH - mean * mean;
  float rstd = rsqrtf(var + 1e-12f);
#pragma unroll
  for (int j = 0; j < 3; ++j) {
    int c = threadIdx.x + j * 256;
    float y = (vals[j] - mean) * rstd * g[c] + be[c];
    of[(long long)row * HD + c] = y;
    ob[(long long)row * HD + c] = (bf16)y;
  }
}

// ---------------------------------------------------------------------------
extern "C" void kernel_launch(void* const* d_in, const int* in_sizes, int n_in,
                              void* d_out, int out_size, void* d_ws, size_t ws_size,
                              hipStream_t stream)
{
  (void)in_sizes; (void)n_in; (void)out_size; (void)ws_size;
  const int*   tok = (const int*)  d_in[0];
  const float* emb = (const float*)d_in[1];
  const float* pos = (const float*)d_in[2];
  const float* wq  = (const float*)d_in[3];
  const float* bq  = (const float*)d_in[4];
  const float* wk  = (const float*)d_in[5];
  const float* bk  = (const float*)d_in[6];
  const float* wv  = (const float*)d_in[7];
  const float* bv  = (const float*)d_in[8];
  const float* wo  = (const float*)d_in[9];
  const float* bo  = (const float*)d_in[10];
  const float* g1  = (const float*)d_in[11];
  const float* be1 = (const float*)d_in[12];
  const float* w1  = (const float*)d_in[13];
  const float* b1  = (const float*)d_in[14];
  const float* w2  = (const float*)d_in[15];
  const float* b2  = (const float*)d_in[16];
  const float* g2  = (const float*)d_in[17];
  const float* be2 = (const float*)d_in[18];
  float* out = (float*)d_out;

  // workspace carve-up
  char* p = (char*)d_ws;
  auto alloc = [&](size_t bytes) {
    char* r = p;
    p += (bytes + 255) & ~(size_t)255;
    return r;
  };
  const long long HH   = (long long)HD * HD;       // 589824
  const long long WPL  = 4 * HH + 2 * (long long)HD * FF; // 7077888 bf16/layer
  const long long MH   = (long long)BB * SS * HD;  // 1572864
  const long long ATT  = (long long)BB * NHD * SS * SS; // 12582912

  bf16*  WT    = (bf16*) alloc((size_t)(WPL * NL) * 2);
  float* bqkv  = (float*)alloc((size_t)NL * 3 * HD * 4);
  float* hf    = (float*)alloc((size_t)MH * 4);
  float* preln = (float*)alloc((size_t)MH * 4);
  bf16*  hb    = (bf16*) alloc((size_t)MH * 2);
  bf16*  qkvb  = (bf16*) alloc((size_t)3 * MH * 2);
  bf16*  vt    = (bf16*) alloc((size_t)MH * 2);
  bf16*  ctxb  = (bf16*) alloc((size_t)MH * 2);
  bf16*  u     = (bf16*) alloc((size_t)BB * SS * FF * 2);

  dim3 tb(32, 8);
  // weights: fp32 [K,N] -> bf16 [N,K] per layer slot
  transpose_cvt<<<dim3(HD/32, HD/32, NL), tb, 0, stream>>>(wq, WT + 0,      HD, HD, HH, WPL);
  transpose_cvt<<<dim3(HD/32, HD/32, NL), tb, 0, stream>>>(wk, WT + HH,     HD, HD, HH, WPL);
  transpose_cvt<<<dim3(HD/32, HD/32, NL), tb, 0, stream>>>(wv, WT + 2*HH,   HD, HD, HH, WPL);
  transpose_cvt<<<dim3(HD/32, HD/32, NL), tb, 0, stream>>>(wo, WT + 3*HH,   HD, HD, HH, WPL);
  transpose_cvt<<<dim3(FF/32, HD/32, NL), tb, 0, stream>>>(w1, WT + 4*HH,   HD, FF, (long long)HD*FF, WPL);
  transpose_cvt<<<dim3(HD/32, FF/32, NL), tb, 0, stream>>>(w2, WT + 4*HH + (long long)HD*FF, FF, HD, (long long)HD*FF, WPL);

  pack_bias<<<dim3((NL * 3 * HD + 255) / 256), 256, 0, stream>>>(bq, bk, bv, bqkv);
  embed_k<<<dim3(BB * SS), 256, 0, stream>>>(tok, emb, pos, hf, hb);

  const long long OUT0 = MH;

  for (int l = 0; l < NL; ++l) {
    const bf16* WQT = WT + (long long)l * WPL;
    const bf16* WOT = WQT + 3 * HH;
    const bf16* W1T = WQT + 4 * HH;
    const bf16* W2T = WQT + 4 * HH + (long long)HD * FF;

    // 1. QKV projections (z=3); zi==2 (V) writes Vt directly. BM=64 -> 576 blocks
    gemm_kernel<64,128,false><<<dim3(HD/128, (BB*SS)/64, 3), 256, 0, stream>>>(
        hb, WQT, HD, HD, HD, HD, 3,
        0, 0, HH, 0, MH, 0,
        bqkv + (long long)l * 3 * HD, HD, nullptr, 1.f, nullptr, qkvb, vt);

    // 2. fused scores + mask + softmax + PV -> fp32 P (d_out slice) + ctx bf16
    attn_fused<<<dim3(SS/64, BB*NHD), 256, 0, stream>>>(
        qkvb, qkvb + MH, vt, tok, out + OUT0 + (long long)l * ATT, ctxb);

    // 3. O-projection + bias + residual(x). 64x64 -> 384 blocks
    gemm_kernel<64,64,false><<<dim3(HD/64, (BB*SS)/64, 1), 256, 0, stream>>>(
        ctxb, WOT, HD, HD, HD, HD, 1,
        0, 0, 0, 0, 0, 0,
        bo + (long long)l * HD, 0, hf, 1.f, preln, nullptr, nullptr);

    // 4. LN1 -> hf, hb
    ln_k<<<dim3(BB*SS), 256, 0, stream>>>(preln, g1 + (long long)l*HD, be1 + (long long)l*HD, hf, hb);

    // 5. FFN1 + bias + relu -> u (bf16). 64x128 -> 768 blocks
    gemm_kernel<64,128,true><<<dim3(FF/128, (BB*SS)/64, 1), 256, 0, stream>>>(
        hb, W1T, HD, HD, HD, FF, 1,
        0, 0, 0, 0, 0, 0,
        b1 + (long long)l * FF, 0, nullptr, 1.f, nullptr, u, nullptr);

    // 6. FFN2 + bias + residual(hf). 64x64 -> 384 blocks, K=3072
    gemm_kernel<64,64,false><<<dim3(HD/64, (BB*SS)/64, 1), 256, 0, stream>>>(
        u, W2T, FF, FF, FF, HD, 1,
        0, 0, 0, 0, 0, 0,
        b2 + (long long)l * HD, 0, hf, 1.f, preln, nullptr, nullptr);

    // 7. LN2 -> (hf or final out), hb
    ln_k<<<dim3(BB*SS), 256, 0, stream>>>(preln, g2 + (long long)l*HD, be2 + (long long)l*HD,
                                          (l == NL - 1) ? out : hf, hb);
  }
}